// Round 17
// baseline (52.954 us; speedup 1.0000x reference)
//
#include <hip/hip_runtime.h>
#include <hip/hip_bf16.h>

// Problem constants
#define BATCH 32768
#define NIN   256
#define NOUT  256
// degrees 1..8 via MFMA; degree 0 (T_0 = 1) folded into per-column bias

typedef __attribute__((ext_vector_type(8))) short bf16x8;
typedef __attribute__((ext_vector_type(4))) float f32x4;
typedef __attribute__((ext_vector_type(2))) float f32x2;
typedef __attribute__((ext_vector_type(4))) unsigned int u32x4;

static __device__ __forceinline__ unsigned short bf16_rne(float f) {
  unsigned u = __float_as_uint(f);
  u += 0x7fffu + ((u >> 16) & 1u);
  return (unsigned short)(u >> 16);
}

// fast tanh: t = sign(v) * (1 - z) / (1 + z), z = exp(-2|v|)
static __device__ __forceinline__ float fast_tanh(float v) {
  float a = fabsf(v);
  float z = __expf(-2.0f * a);
  float r = (1.0f - z) * __builtin_amdgcn_rcpf(1.0f + z);
  return copysignf(r, v);
}

static __device__ __forceinline__ unsigned pack_pair(f32x2 v) {
  __hip_bfloat162 h2 = __float22bfloat162_rn(make_float2(v[0], v[1]));
  union { __hip_bfloat162 h; unsigned u; } cv;
  cv.h = h2;
  return cv.u;
}

static __device__ __forceinline__ void init_state(const f32x4 x0, const f32x4 x1,
                                                  f32x2* cur, f32x2* prev,
                                                  f32x2* t2) {
  #pragma unroll
  for (int p = 0; p < 4; ++p) {
    float va = (p < 2) ? x0[2 * p]     : x1[2 * p - 4];
    float vb = (p < 2) ? x0[2 * p + 1] : x1[2 * p - 3];
    float ta = fast_tanh(va);
    float tb = fast_tanh(vb);
    cur[p]  = (f32x2){ta, tb};        // T_1
    t2[p]   = cur[p] + cur[p];
    prev[p] = (f32x2){1.0f, 1.0f};    // T_0
  }
}

// lgkm-draining barrier (LDS visibility) with scheduler fences
static __device__ __forceinline__ void window_barrier() {
  __builtin_amdgcn_sched_barrier(0);
  asm volatile("s_waitcnt lgkmcnt(0)" ::: "memory");
  __builtin_amdgcn_s_barrier();
  __builtin_amdgcn_sched_barrier(0);
}

// ---------------------------------------------------------------------------
// Merged prepack + bias (ONE launch).
// Grid: 256 blocks (n), 256 threads (i). Writes
//   Bp[((dm*8+ic)*16+tile)*512 + kg*128 + col*8 + j] and bias[n].
// ---------------------------------------------------------------------------
__global__ void cheby_prep(const float* __restrict__ cb,
                           const float* __restrict__ ca,
                           unsigned short* __restrict__ Bp,
                           float* __restrict__ bias) {
  __shared__ float red[256];
  int n = blockIdx.x;
  int i = threadIdx.x;

  const float* cp = cb + ((size_t)n * NIN + i) * 9;
  f32x4 c0 = *(const f32x4*)cp;
  f32x4 c1 = *(const f32x4*)(cp + 4);
  float c8  = cp[8];
  float av  = ca[(size_t)n * NIN + i];

  int ic   = i >> 5;
  int kg   = (i >> 3) & 3;
  int j    = i & 7;
  int tile = n >> 4;
  int col  = n & 15;
  size_t base = (size_t)kg * 128 + col * 8 + j;
  #pragma unroll
  for (int dm = 0; dm < 8; ++dm) {
    float w = ((dm < 3) ? c0[dm + 1] : (dm < 7) ? c1[dm - 3] : c8) * av;
    Bp[(((size_t)dm * 8 + ic) * 16 + tile) * 512 + base] = bf16_rne(w);
  }

  red[i] = c0[0] * av;
  __syncthreads();
  #pragma unroll
  for (int s = 128; s >= 64; s >>= 1) {
    if (i < s) red[i] += red[i + s];
    __syncthreads();
  }
  if (i < 64) {
    float v = red[i];
    #pragma unroll
    for (int off = 32; off; off >>= 1) v += __shfl_down(v, off);
    if (i == 0) bias[n] = v;
  }
}

// ---------------------------------------------------------------------------
// Fused cheby + GEMM with WAVE ROLE-SPLIT (T3 regime).
// Grid: 256 blocks x 512 threads (8 waves), 1 block/CU, LDS 128KB.
// Block tile 128x256; wave tile 64x64 (wr=w>>2, wc=w&3); wave w writes
// basis plane w. 64 windows: step-pair P_k (2 degrees, 32 MFMA);
// even-parity waves MFMA P_k in window 2k (prefetch in odd windows),
// odd-parity waves MFMA P_k in window 2k+1 (prefetch in even windows).
// -> every window has 4 waves on the matrix pipe and 4 on LDS/vmem.
// Per prefetch window: 8 ds_read A + 8 B loads + 2 basis slices.
// All cross-wave LDS write->read pairs are >=5 barriers apart; all A
// writes go to buf^1 of concurrent reads. Waits are compiler-managed.
// ---------------------------------------------------------------------------
__global__ __launch_bounds__(512, 2)
void cheby_mfma(const float* __restrict__ x,
                const unsigned short* __restrict__ Bp,
                const float* __restrict__ bias,
                float* __restrict__ out) {
  // [buf][d][plane 0..7][frag: kg*256B + row16*16B] -- 1KB planes, 128KB
  __shared__ unsigned short Asm_[2][8][8][512];

  int tid  = threadIdx.x;
  int w    = tid >> 6;            // 0..7
  int lane = tid & 63;
  int row16 = lane & 15;
  int kg    = lane >> 4;

  int wr = w >> 2;
  int wc = w & 3;
  int base_row = blockIdx.x * 128;
  int tile0    = wc * 4;
  const bool role0 = ((w & 1) == 0);   // MFMA at even windows

  const float* xw = x + (size_t)(base_row + w * 16 + row16) * NIN + kg * 8;
  char* wbase = (char*)Asm_ + (w * 1024 + lane * 16);
  const char* abase   = (const char*)Asm_ + lane * 16;
  const char* bp_lane = (const char*)Bp + kg * 256 + row16 * 16;

  f32x4 acc[4][4];
  #pragma unroll
  for (int a = 0; a < 4; ++a)
    #pragma unroll
    for (int b = 0; b < 4; ++b) acc[a][b] = (f32x4)0.0f;

  // ---- prologue: full basis(0) -> buf0 ----
  f32x4 xa = *(const f32x4*)xw;
  f32x4 xb = *(const f32x4*)(xw + 4);
  {
    f32x2 c0[4], p0[4], t0[4];
    init_state(xa, xb, c0, p0, t0);
    #pragma unroll
    for (int d = 0; d < 8; ++d) {
      u32x4 pk;
      #pragma unroll
      for (int q = 0; q < 4; ++q) pk[q] = pack_pair(c0[q]);
      *(u32x4*)(wbase + d * 8192) = pk;
      if (d < 7) {
        #pragma unroll
        for (int q = 0; q < 4; ++q) {
          f32x2 nx = __builtin_elementwise_fma(t0[q], c0[q], -p0[q]);
          p0[q] = c0[q];
          c0[q] = nx;
        }
      }
    }
  }
  // x(1) + recurrence state for basis(1)
  xa = *(const f32x4*)(xw + 32);
  xb = *(const f32x4*)(xw + 36);
  f32x2 cur[4], prev[4], t2[4];
  init_state(xa, xb, cur, prev, t2);

  window_barrier();                // basis(0) visible

  // loop-carried prefetch registers (one step-pair deep)
  bf16x8 af2[2][4], bf2[2][4];
  if (role0) {                     // prefetch P_0 before window loop
    const char* a0 = abase + (wr * 4) * 1024;
    const char* b0 = bp_lane + (size_t)tile0 * 1024;
    #pragma unroll
    for (int dd = 0; dd < 2; ++dd) {
      #pragma unroll
      for (int mt = 0; mt < 4; ++mt)
        af2[dd][mt] = *(const bf16x8*)(a0 + dd * 8192 + mt * 1024);
      #pragma unroll
      for (int nt = 0; nt < 4; ++nt)
        bf2[dd][nt] = *(const bf16x8*)(b0 + (size_t)dd * 131072 + nt * 1024);
    }
  }

#define MFMA_PAIR()                                                      \
    __builtin_amdgcn_s_setprio(1);                                       \
    _Pragma("unroll")                                                    \
    for (int dd = 0; dd < 2; ++dd)                                       \
      _Pragma("unroll")                                                  \
      for (int mt = 0; mt < 4; ++mt)                                     \
        _Pragma("unroll")                                                \
        for (int nt = 0; nt < 4; ++nt)                                   \
          acc[mt][nt] = __builtin_amdgcn_mfma_f32_16x16x32_bf16(         \
              af2[dd][mt], bf2[dd][nt], acc[mt][nt], 0, 0, 0);           \
    __builtin_amdgcn_s_setprio(0)

#define PREFETCH_PAIR(ABASE, BBASE, D0)                                  \
    _Pragma("unroll")                                                    \
    for (int dd = 0; dd < 2; ++dd) {                                     \
      _Pragma("unroll")                                                  \
      for (int mt = 0; mt < 4; ++mt)                                     \
        af2[dd][mt] =                                                    \
            *(const bf16x8*)((ABASE) + ((D0) + dd) * 8192 + mt * 1024);  \
      _Pragma("unroll")                                                  \
      for (int nt = 0; nt < 4; ++nt)                                     \
        bf2[dd][nt] = *(const bf16x8*)((BBASE) +                         \
            (size_t)((D0) + dd) * 131072 + nt * 1024);                   \
    }

#define SLICES(Q)                                                        \
    if (ic < 7) {                                                        \
      _Pragma("unroll")                                                  \
      for (int s2 = 0; s2 < 2; ++s2) {                                   \
        u32x4 pk;                                                        \
        _Pragma("unroll")                                                \
        for (int q = 0; q < 4; ++q) pk[q] = pack_pair(cur[q]);           \
        *(u32x4*)(wp + (2 * (Q) + s2) * 8192) = pk;                      \
        if (2 * (Q) + s2 < 7) {                                          \
          _Pragma("unroll")                                              \
          for (int q = 0; q < 4; ++q) {                                  \
            f32x2 nx =                                                   \
                __builtin_elementwise_fma(t2[q], cur[q], -prev[q]);      \
            prev[q] = cur[q];                                            \
            cur[q]  = nx;                                                \
          }                                                              \
        }                                                                \
      }                                                                  \
    }

  // ---- main loop: 8 spans x 8 windows ----
  for (int ic = 0; ic < 8; ++ic) {
    const char* ai   = abase + (ic & 1) * 65536 + (wr * 4) * 1024;
    const char* ain  = abase + ((ic + 1) & 1) * 65536 + (wr * 4) * 1024;
    char*       wp   = wbase + ((ic + 1) & 1) * 65536;
    const char* bpi  = bp_lane + (size_t)(ic * 16 + tile0) * 1024;
    const char* bpin = bp_lane + (size_t)((ic + 1) * 16 + tile0) * 1024;

    #pragma unroll
    for (int l = 0; l < 8; ++l) {
      if (role0) {
        if ((l & 1) == 0) {            // MFMA steps (l, l+1)
          MFMA_PAIR();
        } else {                       // prefetch + slices
          if (l < 7) {
            PREFETCH_PAIR(ai, bpi, l + 1);      // steps (l+1, l+2)
          } else if (ic < 7) {
            PREFETCH_PAIR(ain, bpin, 0);        // steps (0,1) of ic+1
          }
          SLICES(l >> 1);
        }
      } else {
        if ((l & 1) == 0) {            // prefetch steps (l, l+1) + slices
          PREFETCH_PAIR(ai, bpi, l);
          SLICES(l >> 1);
        } else {                       // MFMA steps (l-1, l)
          MFMA_PAIR();
        }
      }
      if (l == 3 && ic <= 5) {         // x(ic+2)
        xa = *(const f32x4*)(xw + (ic + 2) * 32);
        xb = *(const f32x4*)(xw + (ic + 2) * 32 + 4);
      }
      if (l == 7 && ic <= 5)           // state for basis(ic+2)
        init_state(xa, xb, cur, prev, t2);

      if (!(ic == 7 && l == 7)) window_barrier();
    }
  }
#undef SLICES
#undef PREFETCH_PAIR
#undef MFMA_PAIR

  // epilogue: C/D layout col = lane&15, row = (lane>>4)*4 + q  (m89/m91)
  #pragma unroll
  for (int nt = 0; nt < 4; ++nt) {
    int c = (tile0 + nt) * 16 + row16;
    float bv = bias[c];
    #pragma unroll
    for (int mt = 0; mt < 4; ++mt) {
      int r0 = base_row + wr * 64 + mt * 16 + kg * 4;
      #pragma unroll
      for (int q = 0; q < 4; ++q)
        out[(size_t)(r0 + q) * NOUT + c] = acc[mt][nt][q] + bv;
    }
  }
}

extern "C" void kernel_launch(void* const* d_in, const int* in_sizes, int n_in,
                              void* d_out, int out_size, void* d_ws, size_t ws_size,
                              hipStream_t stream) {
  const float* x  = (const float*)d_in[0];
  const float* cb = (const float*)d_in[1];   // c_basis (256,256,9)
  const float* ca = (const float*)d_in[2];   // c_act   (256,256)
  float* out = (float*)d_out;

  unsigned short* Bp = (unsigned short*)d_ws;                    // 1 MB
  float* bias = (float*)((char*)d_ws + 8 * NIN * NOUT * 2);      // 1 KB

  cheby_prep<<<NOUT, 256, 0, stream>>>(cb, ca, Bp, bias);
  cheby_mfma<<<256, 512, 0, stream>>>(x, Bp, bias, out);
}

// Round 18
// 45.309 us; speedup vs baseline: 1.1687x; 1.1687x over previous
//
#include <hip/hip_runtime.h>
#include <hip/hip_bf16.h>

// Problem constants
#define BATCH 32768
#define NIN   256
#define NOUT  256
// degrees 1..8 via MFMA; degree 0 (T_0 = 1) folded into per-column bias

typedef __attribute__((ext_vector_type(8))) short bf16x8;
typedef __attribute__((ext_vector_type(4))) float f32x4;
typedef __attribute__((ext_vector_type(2))) float f32x2;
typedef __attribute__((ext_vector_type(4))) unsigned int u32x4;

static __device__ __forceinline__ unsigned short bf16_rne(float f) {
  unsigned u = __float_as_uint(f);
  u += 0x7fffu + ((u >> 16) & 1u);
  return (unsigned short)(u >> 16);
}

// fast tanh: t = sign(v) * (1 - z) / (1 + z), z = exp(-2|v|)
static __device__ __forceinline__ float fast_tanh(float v) {
  float a = fabsf(v);
  float z = __expf(-2.0f * a);
  float r = (1.0f - z) * __builtin_amdgcn_rcpf(1.0f + z);
  return copysignf(r, v);
}

static __device__ __forceinline__ unsigned pack_pair(f32x2 v) {
  __hip_bfloat162 h2 = __float22bfloat162_rn(make_float2(v[0], v[1]));
  union { __hip_bfloat162 h; unsigned u; } cv;
  cv.h = h2;
  return cv.u;
}

static __device__ __forceinline__ void init_state(const f32x4 x0, const f32x4 x1,
                                                  f32x2* cur, f32x2* prev,
                                                  f32x2* t2) {
  #pragma unroll
  for (int p = 0; p < 4; ++p) {
    float va = (p < 2) ? x0[2 * p]     : x1[2 * p - 4];
    float vb = (p < 2) ? x0[2 * p + 1] : x1[2 * p - 3];
    float ta = fast_tanh(va);
    float tb = fast_tanh(vb);
    cur[p]  = (f32x2){ta, tb};        // T_1
    t2[p]   = cur[p] + cur[p];
    prev[p] = (f32x2){1.0f, 1.0f};    // T_0
  }
}

// raw barrier (no vmcnt drain) with scheduler fences
static __device__ __forceinline__ void phase_barrier() {
  __builtin_amdgcn_sched_barrier(0);
  __builtin_amdgcn_s_barrier();
  __builtin_amdgcn_sched_barrier(0);
}

// ---------------------------------------------------------------------------
// Merged prepack + bias (ONE launch).
// Grid: 256 blocks (one per output column n), 256 threads (one per input i).
// Thread (n,i): loads cb[n][i][0..8] and ca[n][i];
//   - writes 8 prepacked bf16 weights into the MFMA fragment layout:
//       Bp[((dm*8+ic)*16+tile)*512 + kg*128 + col*8 + j],
//       ic=i>>5, kg=(i>>3)&3, j=i&7, tile=n>>4, col=n&15
//   - contributes cb[n][i][0]*ca[n][i] to bias[n] via block reduction.
// ---------------------------------------------------------------------------
__global__ void cheby_prep(const float* __restrict__ cb,
                           const float* __restrict__ ca,
                           unsigned short* __restrict__ Bp,
                           float* __restrict__ bias) {
  __shared__ float red[256];
  int n = blockIdx.x;
  int i = threadIdx.x;

  const float* cp = cb + ((size_t)n * NIN + i) * 9;
  f32x4 c0 = *(const f32x4*)cp;
  f32x4 c1 = *(const f32x4*)(cp + 4);
  float c8  = cp[8];
  float av  = ca[(size_t)n * NIN + i];

  int ic   = i >> 5;
  int kg   = (i >> 3) & 3;
  int j    = i & 7;
  int tile = n >> 4;
  int col  = n & 15;
  size_t base = (size_t)kg * 128 + col * 8 + j;
  #pragma unroll
  for (int dm = 0; dm < 8; ++dm) {
    float w = ((dm < 3) ? c0[dm + 1] : (dm < 7) ? c1[dm - 3] : c8) * av;
    Bp[(((size_t)dm * 8 + ic) * 16 + tile) * 512 + base] = bf16_rne(w);
  }

  red[i] = c0[0] * av;
  __syncthreads();
  #pragma unroll
  for (int s = 128; s >= 64; s >>= 1) {
    if (i < s) red[i] += red[i + s];
    __syncthreads();
  }
  if (i < 64) {
    float v = red[i];
    #pragma unroll
    for (int off = 32; off; off >>= 1) v += __shfl_down(v, off);
    if (i == 0) bias[n] = v;
  }
}

// ---------------------------------------------------------------------------
// Fused cheby + GEMM, 8-phase pipelined, 128-row blocks (best verified).
// Grid: 256 blocks x 512 threads (8 waves) -> 1 block/CU, LDS 128KB.
// Block tile: 128 rows x 256 cols. Wave tile: 64x64 (wr=w>>2 row half,
// wc=w&3 col strip). Basis computed exactly once per x element (wave w
// writes plane w). Per phase: { ds_read A(next) || 4 B-loads(next) ||
// basis slice(ic+1) } -> s_barrier -> 16 MFMA.
// ---------------------------------------------------------------------------
__global__ __launch_bounds__(512, 2)
void cheby_mfma(const float* __restrict__ x,
                const unsigned short* __restrict__ Bp,
                const float* __restrict__ bias,
                float* __restrict__ out) {
  // [buf][d-1][plane 0..7][frag: kg*256B + row16*16B] -- 1KB planes, 128KB
  __shared__ unsigned short Asm_[2][8][8][512];

  int tid  = threadIdx.x;
  int w    = tid >> 6;            // 0..7
  int lane = tid & 63;
  int row16 = lane & 15;          // A row / B col / C-D col
  int kg    = lane >> 4;          // k-group 0..3

  int wr = w >> 2;                // row half (0..1)
  int wc = w & 3;                 // col strip (0..3)
  int base_row = blockIdx.x * 128;
  int tile0    = wc * 4;          // wave's 4 column tiles (64 cols)

  // writer role: wave w covers rows w*16..w*16+15 (plane w)
  const float* xw = x + (size_t)(base_row + w * 16 + row16) * NIN + kg * 8;
  char* wbase = (char*)Asm_ + (w * 1024 + lane * 16);  // + d*8192 + buf*65536
  // reader
  const char* abase   = (const char*)Asm_ + lane * 16;
  const char* bp_lane = (const char*)Bp + kg * 256 + row16 * 16;

  f32x4 acc[4][4];
  #pragma unroll
  for (int a = 0; a < 4; ++a)
    #pragma unroll
    for (int b = 0; b < 4; ++b) acc[a][b] = (f32x4)0.0f;

  // ---- prologue: full basis(0) -> buf0 ----
  f32x4 xa = *(const f32x4*)xw;
  f32x4 xb = *(const f32x4*)(xw + 4);
  {
    f32x2 c0[4], p0[4], t0[4];
    init_state(xa, xb, c0, p0, t0);
    #pragma unroll
    for (int d = 1; d <= 8; ++d) {
      u32x4 pk;
      #pragma unroll
      for (int q = 0; q < 4; ++q) pk[q] = pack_pair(c0[q]);
      *(u32x4*)(wbase + (d - 1) * 8192) = pk;
      if (d < 8) {
        #pragma unroll
        for (int q = 0; q < 4; ++q) {
          f32x2 nx = __builtin_elementwise_fma(t0[q], c0[q], -p0[q]);
          p0[q] = c0[q];
          c0[q] = nx;
        }
      }
    }
  }
  // x(1) + recurrence state for basis(1)
  xa = *(const f32x4*)(xw + 32);
  xb = *(const f32x4*)(xw + 36);
  f32x2 cur[4], prev[4], t2[4];
  init_state(xa, xb, cur, prev, t2);

  bf16x8 af[2][4], bfr[2][4];
  // B for step (0,0)
  {
    const char* bp0 = bp_lane + (size_t)tile0 * 1024;
    #pragma unroll
    for (int nt = 0; nt < 4; ++nt)
      bfr[0][nt] = *(const bf16x8*)(bp0 + nt * 1024);
  }
  // make basis(0) visible, then read A(0,0)
  __builtin_amdgcn_sched_barrier(0);
  asm volatile("s_waitcnt lgkmcnt(0)" ::: "memory");
  __builtin_amdgcn_s_barrier();
  __builtin_amdgcn_sched_barrier(0);
  #pragma unroll
  for (int mt = 0; mt < 4; ++mt)
    af[0][mt] = *(const bf16x8*)(abase + (wr * 4 + mt) * 1024);

  // ---- main loop: ic = 0..6 (basis for ic+1 distributed over 8 phases) ----
  for (int ic = 0; ic < 7; ++ic) {
    const char* ai   = abase + (ic & 1) * 65536 + (wr * 4) * 1024;
    const char* ain  = abase + ((ic + 1) & 1) * 65536 + (wr * 4) * 1024;
    char*       wp   = wbase + ((ic + 1) & 1) * 65536;
    const char* bpi  = bp_lane + (size_t)(ic * 16 + tile0) * 1024;
    const char* bpin = bp_lane + (size_t)((ic + 1) * 16 + tile0) * 1024;

    #pragma unroll
    for (int p = 0; p < 8; ++p) {
      // A-frags for next step
      if (p < 7) {
        #pragma unroll
        for (int mt = 0; mt < 4; ++mt)
          af[(p + 1) & 1][mt] =
              *(const bf16x8*)(ai + (p + 1) * 8192 + mt * 1024);
      } else {
        #pragma unroll
        for (int mt = 0; mt < 4; ++mt)
          af[0][mt] = *(const bf16x8*)(ain + mt * 1024);
      }
      // B-frags for next step (1 phase deep, counted vmcnt at use)
      if (p < 7) {
        #pragma unroll
        for (int nt = 0; nt < 4; ++nt)
          bfr[(p + 1) & 1][nt] =
              *(const bf16x8*)(bpi + (size_t)(p + 1) * 131072 + nt * 1024);
      } else {
        #pragma unroll
        for (int nt = 0; nt < 4; ++nt)
          bfr[0][nt] = *(const bf16x8*)(bpin + nt * 1024);
      }
      // basis degree-slice: write T_{p+1}(ic+1), advance recurrence
      {
        u32x4 pk;
        #pragma unroll
        for (int q = 0; q < 4; ++q) pk[q] = pack_pair(cur[q]);
        *(u32x4*)(wp + p * 8192) = pk;
        if (p < 7) {
          #pragma unroll
          for (int q = 0; q < 4; ++q) {
            f32x2 nx = __builtin_elementwise_fma(t2[q], cur[q], -prev[q]);
            prev[q] = cur[q];
            cur[q]  = nx;
          }
        }
      }
      if (p == 3 && ic <= 5) {     // x for ic+2 (used at p==7)
        xa = *(const f32x4*)(xw + (ic + 2) * 32);
        xb = *(const f32x4*)(xw + (ic + 2) * 32 + 4);
      }
      if (p == 7 && ic <= 5)       // state for basis(ic+2)
        init_state(xa, xb, cur, prev, t2);

      phase_barrier();

      __builtin_amdgcn_s_setprio(1);
      #pragma unroll
      for (int mt = 0; mt < 4; ++mt)
        #pragma unroll
        for (int nt = 0; nt < 4; ++nt)
          acc[mt][nt] = __builtin_amdgcn_mfma_f32_16x16x32_bf16(
              af[p & 1][mt], bfr[p & 1][nt], acc[mt][nt], 0, 0, 0);
      __builtin_amdgcn_s_setprio(0);
    }
  }

  // ---- final ic = 7: no basis work, no barriers ----
  {
    const char* ai  = abase + 65536 + (wr * 4) * 1024;   // buf1
    const char* bpi = bp_lane + (size_t)(7 * 16 + tile0) * 1024;
    #pragma unroll
    for (int p = 0; p < 8; ++p) {
      if (p < 7) {
        #pragma unroll
        for (int mt = 0; mt < 4; ++mt)
          af[(p + 1) & 1][mt] =
              *(const bf16x8*)(ai + (p + 1) * 8192 + mt * 1024);
        #pragma unroll
        for (int nt = 0; nt < 4; ++nt)
          bfr[(p + 1) & 1][nt] =
              *(const bf16x8*)(bpi + (size_t)(p + 1) * 131072 + nt * 1024);
      }
      __builtin_amdgcn_s_setprio(1);
      #pragma unroll
      for (int mt = 0; mt < 4; ++mt)
        #pragma unroll
        for (int nt = 0; nt < 4; ++nt)
          acc[mt][nt] = __builtin_amdgcn_mfma_f32_16x16x32_bf16(
              af[p & 1][mt], bfr[p & 1][nt], acc[mt][nt], 0, 0, 0);
      __builtin_amdgcn_s_setprio(0);
    }
  }

  // epilogue: C/D layout col = lane&15, row = (lane>>4)*4 + q  (m89/m91)
  #pragma unroll
  for (int nt = 0; nt < 4; ++nt) {
    int c = (tile0 + nt) * 16 + row16;
    float bv = bias[c];
    #pragma unroll
    for (int mt = 0; mt < 4; ++mt) {
      int r0 = base_row + wr * 64 + mt * 16 + kg * 4;
      #pragma unroll
      for (int q = 0; q < 4; ++q)
        out[(size_t)(r0 + q) * NOUT + c] = acc[mt][nt][q] + bv;
    }
  }
}

extern "C" void kernel_launch(void* const* d_in, const int* in_sizes, int n_in,
                              void* d_out, int out_size, void* d_ws, size_t ws_size,
                              hipStream_t stream) {
  const float* x  = (const float*)d_in[0];
  const float* cb = (const float*)d_in[1];   // c_basis (256,256,9)
  const float* ca = (const float*)d_in[2];   // c_act   (256,256)
  float* out = (float*)d_out;

  unsigned short* Bp = (unsigned short*)d_ws;                    // 1 MB
  float* bias = (float*)((char*)d_ws + 8 * NIN * NOUT * 2);      // 1 KB

  cheby_prep<<<NOUT, 256, 0, stream>>>(cb, ca, Bp, bias);
  cheby_mfma<<<256, 512, 0, stream>>>(x, Bp, bias, out);
}